// Round 10
// baseline (305.498 us; speedup 1.0000x reference)
//
#include <hip/hip_runtime.h>
#include <math.h>

#define HID 4096
#define NH 32
#define HD 128
#define BB 8
#define SS 8
#define MM 64              // B*S rows
#define MAXT 4096
#define QKV_N (3*HID)      // 12288
#define GBK 64             // GEMM K-step
#define ASTR 72            // GEMM LDS row stride (bf16)

// attention geometry
#define ATILE 64                 // K/V rows per staged tile
#define ACHUNK 1024              // t-rows per block
#define NCHUNK (MAXT/ACHUNK)     // 4
#define NTILES (ACHUNK/ATILE)    // 16
#define NPART (NCHUNK*4)         // partials per (b,h) = 16
#define KSTR 136                 // K LDS row stride (bf16)
#define VSTR 72                  // V^T LDS t-stride (bf16)

typedef __attribute__((ext_vector_type(8))) __bf16 bf16x8;
typedef __attribute__((ext_vector_type(4))) __bf16 bf16x4;
typedef __attribute__((ext_vector_type(4))) float f32x4;
typedef __attribute__((ext_vector_type(4))) short s16x4;

__device__ __forceinline__ float wred_sum(float v) {
#pragma unroll
    for (int i = 1; i < 64; i <<= 1) v += __shfl_xor(v, i, 64);
    return v;
}
__device__ __forceinline__ short bf16bits(float x) {
    __bf16 h = (__bf16)x;
    return __builtin_bit_cast(short, h);
}

// -------------------- LayerNorm: 64 rows of 4096 --------------------
__global__ __launch_bounds__(256)
void ln_kernel(const float* __restrict__ tokens, const float* __restrict__ gamma,
               const float* __restrict__ beta, float* __restrict__ xout) {
    const int row = blockIdx.x;
    const float* in = tokens + (size_t)row * HID;
    float* out = xout + (size_t)row * HID;
    const int tid = threadIdx.x;
    float s = 0.f, s2 = 0.f;
    float4 vals[4];
#pragma unroll
    for (int i = 0; i < 4; ++i) {
        float4 v = *(const float4*)(in + (size_t)(i*256 + tid)*4);
        vals[i] = v;
        s  += v.x + v.y + v.z + v.w;
        s2 += v.x*v.x + v.y*v.y + v.z*v.z + v.w*v.w;
    }
    s = wred_sum(s); s2 = wred_sum(s2);
    __shared__ float red[8];
    int wid = tid >> 6, lane = tid & 63;
    if (lane == 0) { red[wid] = s; red[4+wid] = s2; }
    __syncthreads();
    s  = red[0]+red[1]+red[2]+red[3];
    s2 = red[4]+red[5]+red[6]+red[7];
    float mean = s * (1.f/HID);
    float var  = s2 * (1.f/HID) - mean*mean;
    float rstd = rsqrtf(var + 1e-5f);
#pragma unroll
    for (int i = 0; i < 4; ++i) {
        int base = (i*256 + tid)*4;
        float4 v = vals[i];
        float4 g  = *(const float4*)(gamma + base);
        float4 bt = *(const float4*)(beta + base);
        float4 o;
        o.x = (v.x - mean)*rstd*g.x + bt.x;
        o.y = (v.y - mean)*rstd*g.y + bt.y;
        o.z = (v.z - mean)*rstd*g.z + bt.z;
        o.w = (v.w - mean)*rstd*g.w + bt.w;
        *(float4*)(out + base) = o;
    }
}

// ---------- split-bf16 MFMA GEMM (unchanged from r8) ----------
__global__ __launch_bounds__(256, 3)
void gemm_mfma(const float* __restrict__ x, const float* __restrict__ w,
               float* __restrict__ part, int N, int K, int kparts) {
    __shared__ __bf16 a_hi[64*ASTR], a_lo[64*ASTR];
    __shared__ __bf16 b_hi[64*ASTR], b_lo[64*ASTR];
    const int n0 = blockIdx.x * 64;
    const int kc = blockIdx.y;
    const int kLen = K / kparts;
    const int kBeg = kc * kLen;
    const int tid = threadIdx.x;
    const int wv = tid >> 6;
    const int lane = tid & 63;
    const int wm = (wv & 1) * 32;
    const int wn = (wv >> 1) * 32;
    const int sr = tid >> 2;
    const int sk = (tid & 3) * 16;
    const int fm = lane & 15;
    const int fk = (lane >> 4) * 8;

    f32x4 acc[2][2] = {};
    const float* xsrc = x + (size_t)sr * K + kBeg + sk;
    const float* wsrc = w + (size_t)(n0 + sr) * K + kBeg + sk;

    float aRg[16], bRg[16];
#pragma unroll
    for (int q = 0; q < 4; ++q) {
        *(float4*)&aRg[q*4] = *(const float4*)(xsrc + q*4);
        *(float4*)&bRg[q*4] = *(const float4*)(wsrc + q*4);
    }
    const int nsteps = kLen / GBK;
    for (int st = 0; st < nsteps; ++st) {
        __syncthreads();
#pragma unroll
        for (int q = 0; q < 2; ++q) {
            bf16x8 ah, al, bh, bl;
#pragma unroll
            for (int j = 0; j < 8; ++j) {
                float av = aRg[q*8+j];
                __bf16 h = (__bf16)av;
                ah[j] = h;
                al[j] = (__bf16)(av - (float)h);
                float bv = bRg[q*8+j];
                __bf16 g = (__bf16)bv;
                bh[j] = g;
                bl[j] = (__bf16)(bv - (float)g);
            }
            int base = sr*ASTR + sk + q*8;
            *(bf16x8*)&a_hi[base] = ah;
            *(bf16x8*)&a_lo[base] = al;
            *(bf16x8*)&b_hi[base] = bh;
            *(bf16x8*)&b_lo[base] = bl;
        }
        __syncthreads();
        if (st + 1 < nsteps) {
            const float* xn = xsrc + (size_t)(st+1)*GBK;
            const float* wn_ = wsrc + (size_t)(st+1)*GBK;
#pragma unroll
            for (int q = 0; q < 4; ++q) {
                *(float4*)&aRg[q*4] = *(const float4*)(xn + q*4);
                *(float4*)&bRg[q*4] = *(const float4*)(wn_ + q*4);
            }
        }
#pragma unroll
        for (int kh = 0; kh < 2; ++kh) {
            bf16x8 Ah[2], Al[2], Bh[2], Bl[2];
#pragma unroll
            for (int t = 0; t < 2; ++t) {
                int ar = (wm + t*16 + fm)*ASTR + kh*32 + fk;
                Ah[t] = *(const bf16x8*)&a_hi[ar];
                Al[t] = *(const bf16x8*)&a_lo[ar];
                int br = (wn + t*16 + fm)*ASTR + kh*32 + fk;
                Bh[t] = *(const bf16x8*)&b_hi[br];
                Bl[t] = *(const bf16x8*)&b_lo[br];
            }
#pragma unroll
            for (int mt = 0; mt < 2; ++mt)
#pragma unroll
            for (int nt = 0; nt < 2; ++nt) {
                acc[mt][nt] = __builtin_amdgcn_mfma_f32_16x16x32_bf16(Ah[mt], Bh[nt], acc[mt][nt], 0, 0, 0);
                acc[mt][nt] = __builtin_amdgcn_mfma_f32_16x16x32_bf16(Ah[mt], Bl[nt], acc[mt][nt], 0, 0, 0);
                acc[mt][nt] = __builtin_amdgcn_mfma_f32_16x16x32_bf16(Al[mt], Bh[nt], acc[mt][nt], 0, 0, 0);
            }
        }
    }
    float* dst = part + (size_t)kc * MM * N;
#pragma unroll
    for (int mt = 0; mt < 2; ++mt)
#pragma unroll
    for (int nt = 0; nt < 2; ++nt) {
        int m = wm + mt*16 + (lane >> 4)*4;
        int n = n0 + wn + nt*16 + (lane & 15);
#pragma unroll
        for (int r = 0; r < 4; ++r)
            dst[(size_t)(m + r) * N + n] = acc[mt][nt][r];
    }
}

// ---------------- sum nparts partials + bias ----------------
__global__ __launch_bounds__(256)
void combine_bias(const float* __restrict__ part, const float* __restrict__ bias,
                  float* __restrict__ out, int N, int totalv4, int nparts) {
    int idx = blockIdx.x * 256 + threadIdx.x;
    if (idx >= totalv4) return;
    size_t base = (size_t)idx * 4;
    size_t MN = (size_t)MM * N;
    float4 o = make_float4(0.f,0.f,0.f,0.f);
    for (int p = 0; p < nparts; ++p) {
        float4 a = *(const float4*)(part + (size_t)p * MN + base);
        o.x += a.x; o.y += a.y; o.z += a.z; o.w += a.w;
    }
    int n = (int)(base % (size_t)N);
    float4 bb = *(const float4*)(bias + n);
    o.x += bb.x; o.y += bb.y; o.z += bb.z; o.w += bb.w;
    *(float4*)(out + base) = o;
}

// ---------------- MFMA flash attention partial ----------------
// r10: r9's k=16 PV (lane-local P, no p_lds/pads) with the STAGING BUG fixed:
// full 64-row coverage needs 8 K + 8 V float4/thread (64rows x 32f4 / 256thr).
// launch_bounds(256,3): VGPR cap ~170, live ~150 -> no spill; 3 blocks/CU.
__global__ __launch_bounds__(256, 3)
void attn_part(const float* __restrict__ qkv, const float* __restrict__ cache_k,
               const float* __restrict__ cache_v, const int* __restrict__ d_start,
               float* __restrict__ accp, float* __restrict__ mlp) {
    __shared__ __bf16 k_lds[ATILE*KSTR];   // 17408 B  [t][d]
    __shared__ __bf16 v_lds[HD*VSTR];      // 18432 B  [d][t] (transposed)
    const int bh = blockIdx.x;
    const int b = bh >> 5, h = bh & 31;
    const int c = blockIdx.y;
    const int tid = threadIdx.x;
    const int w = tid >> 6;
    const int lane = tid & 63;
    const int l15 = lane & 15;
    const int lg  = lane >> 4;          // frag quadrant 0..3
    const int woff = w * 16;            // wave's t-rows within tile
    const int start = d_start[0];
    const int T = start + SS;
    const float scale = 0.08838834764831845f;   // 1/sqrt(128)

    const int tq = tid >> 5;            // staging rows tq*8..tq*8+8 (0..63 total)
    const int d4 = (tid & 31) * 4;      // staging d offset

    const size_t cacheRowBase = ((size_t)b*MAXT*NH + h) * (size_t)HD;
    const int cbase = c * ACHUNK;

    float4 kreg[8], vreg[8];
#define LOAD_TILE(TB)                                                             \
    {                                                                             \
        _Pragma("unroll")                                                         \
        for (int j = 0; j < 8; ++j) {                                             \
            int tg = (TB) + tq*8 + j;                                             \
            bool fresh = (tg >= start) && (tg < T);                               \
            const float* kp = fresh                                               \
                ? (qkv + (size_t)(b*SS + (tg-start))*QKV_N + h*HD + HID)          \
                : (cache_k + cacheRowBase + (size_t)tg*NH*HD);                    \
            const float* vp = fresh                                               \
                ? (qkv + (size_t)(b*SS + (tg-start))*QKV_N + h*HD + 2*HID)        \
                : (cache_v + cacheRowBase + (size_t)tg*NH*HD);                    \
            kreg[j] = *(const float4*)(kp + d4);                                  \
            vreg[j] = *(const float4*)(vp + d4);                                  \
        }                                                                         \
    }

    // ---- prologue: Q fragments (regs for whole kernel) ----
    bf16x8 qf[4];
    if (l15 < SS) {
        const float* qp = qkv + (size_t)(b*SS + l15)*QKV_N + h*HD + lg*8;
#pragma unroll
        for (int ks = 0; ks < 4; ++ks) {
            float4 a = *(const float4*)(qp + ks*32);
            float4 b2 = *(const float4*)(qp + ks*32 + 4);
            bf16x8 q8;
            q8[0]=(__bf16)a.x;  q8[1]=(__bf16)a.y;  q8[2]=(__bf16)a.z;  q8[3]=(__bf16)a.w;
            q8[4]=(__bf16)b2.x; q8[5]=(__bf16)b2.y; q8[6]=(__bf16)b2.z; q8[7]=(__bf16)b2.w;
            qf[ks] = q8;
        }
    } else {
#pragma unroll
        for (int ks = 0; ks < 4; ++ks) qf[ks] = (bf16x8)(__bf16)0.0f;
    }
    LOAD_TILE(cbase);
    __syncthreads();

    float m_r = -1e30f, l_r = 0.f;
    f32x4 oacc[8] = {};

    for (int tile = 0; tile < NTILES; ++tile) {
        const int tbase = cbase + tile*ATILE;
        // ---- convert staged regs -> LDS (K row-major bf16, V transposed) ----
#pragma unroll
        for (int j = 0; j < 8; ++j) {
            bf16x4 kb;
            kb[0]=(__bf16)kreg[j].x; kb[1]=(__bf16)kreg[j].y;
            kb[2]=(__bf16)kreg[j].z; kb[3]=(__bf16)kreg[j].w;
            *(bf16x4*)&k_lds[(tq*8+j)*KSTR + d4] = kb;
        }
#pragma unroll
        for (int i = 0; i < 4; ++i) {
            bf16x8 vt;
#pragma unroll
            for (int j = 0; j < 8; ++j)
                vt[j] = (__bf16)(((const float*)&vreg[j])[i]);
            *(bf16x8*)&v_lds[(d4 + i)*VSTR + tq*8] = vt;
        }
        __syncthreads();   // tile LDS ready
        if (tile + 1 < NTILES) LOAD_TILE(tbase + ATILE);   // lands under compute

        // ---- QK^T (k=32): D[t_loc=lg*4+r][s=l15] ----
        f32x4 sacc = {0.f, 0.f, 0.f, 0.f};
#pragma unroll
        for (int ks = 0; ks < 4; ++ks) {
            bf16x8 kf = *(const bf16x8*)&k_lds[(woff + l15)*KSTR + ks*32 + lg*8];
            sacc = __builtin_amdgcn_mfma_f32_16x16x32_bf16(kf, qf[ks], sacc, 0, 0, 0);
        }
        // ---- online softmax (per wave; lane: s=l15, t=lg*4+r) ----
        float sc[4]; bool val[4];
#pragma unroll
        for (int r = 0; r < 4; ++r) {
            int tg = tbase + woff + lg*4 + r;
            val[r] = tg < T;
            sc[r] = val[r] ? sacc[r]*scale : -1e30f;
        }
        float tmax = fmaxf(fmaxf(sc[0], sc[1]), fmaxf(sc[2], sc[3]));
        tmax = fmaxf(tmax, __shfl_xor(tmax, 16, 64));
        tmax = fmaxf(tmax, __shfl_xor(tmax, 32, 64));
        float mn = fmaxf(m_r, tmax);
        float al = __expf(m_r - mn);
        float p[4];
#pragma unroll
        for (int r = 0; r < 4; ++r) p[r] = val[r] ? __expf(sc[r] - mn) : 0.f;
        float psum = (p[0]+p[1]) + (p[2]+p[3]);
        psum += __shfl_xor(psum, 16, 64);
        psum += __shfl_xor(psum, 32, 64);
        l_r = l_r * al + psum;
        m_r = mn;
        // ---- PV (k=16): pa = own p (A[m=s=l15][k=t=lg*4+j] = p[j]) ----
        s16x4 pa;
        pa[0]=bf16bits(p[0]); pa[1]=bf16bits(p[1]);
        pa[2]=bf16bits(p[2]); pa[3]=bf16bits(p[3]);
        // rescale oacc rows (s=lg*4+r) by their alpha
        float als[4];
#pragma unroll
        for (int r = 0; r < 4; ++r) als[r] = __shfl(al, lg*4 + r, 64);
#pragma unroll
        for (int dt = 0; dt < 8; ++dt) {
            oacc[dt][0] *= als[0]; oacc[dt][1] *= als[1];
            oacc[dt][2] *= als[2]; oacc[dt][3] *= als[3];
        }
#pragma unroll
        for (int dt = 0; dt < 8; ++dt) {
            s16x4 vb = *(const s16x4*)&v_lds[(dt*16 + l15)*VSTR + woff + lg*4];
            oacc[dt] = __builtin_amdgcn_mfma_f32_16x16x16bf16_1k(pa, vb, oacc[dt], 0, 0, 0);
        }
        __syncthreads();   // all readers done before next convert
    }

    // ---- store per-wave partial: acc rows s<8, m, l ----
    const int pidx = (bh*NCHUNK + c)*4 + w;
    float* abase = accp + (size_t)pidx * SS * HD;
#pragma unroll
    for (int r = 0; r < 4; ++r) {
        int s = lg*4 + r;
        if (s < SS) {
#pragma unroll
            for (int dt = 0; dt < 8; ++dt)
                abase[(size_t)s*HD + dt*16 + l15] = oacc[dt][r];
        }
    }
    if (lane < SS) {
        mlp[(size_t)pidx*16 + lane] = m_r;
        mlp[(size_t)pidx*16 + 8 + lane] = l_r;
    }
#undef LOAD_TILE
}

// ---------------- combine NPART partials -> attn_out (64 x 4096) ----------------
__global__ __launch_bounds__(256)
void attn_combine(const float* __restrict__ accp, const float* __restrict__ mlp,
                  float* __restrict__ attn_out) {
    const int bh = blockIdx.x;
    const int b = bh >> 5, h = bh & 31;
    const int tid = threadIdx.x;
    const int s = tid >> 5, dg = tid & 31;
    float mC[NPART], lC[NPART];
    float M = -1e30f;
#pragma unroll
    for (int p = 0; p < NPART; ++p) {
        size_t mb = (size_t)(bh*NPART + p) * 16;
        mC[p] = mlp[mb + s];
        lC[p] = mlp[mb + 8 + s];
        M = fmaxf(M, mC[p]);
    }
    float L = 0.f;
    float4 o = make_float4(0.f,0.f,0.f,0.f);
#pragma unroll
    for (int p = 0; p < NPART; ++p) {
        float wgt = __expf(mC[p] - M);
        L += wgt * lC[p];
        float4 a = *(const float4*)(accp + ((size_t)(bh*NPART + p) * SS + s) * HD + dg*4);
        o.x += wgt*a.x; o.y += wgt*a.y; o.z += wgt*a.z; o.w += wgt*a.w;
    }
    float inv = 1.f / L;
    o.x *= inv; o.y *= inv; o.z *= inv; o.w *= inv;
    *(float4*)(attn_out + (size_t)(b*SS + s)*HID + h*HD + dg*4) = o;
}

extern "C" void kernel_launch(void* const* d_in, const int* in_sizes, int n_in,
                              void* d_out, int out_size, void* d_ws, size_t ws_size,
                              hipStream_t stream) {
    const float* tokens  = (const float*)d_in[0];
    const float* cache_k = (const float*)d_in[1];
    const float* cache_v = (const float*)d_in[2];
    const float* gamma   = (const float*)d_in[3];
    const float* beta    = (const float*)d_in[4];
    const float* qkv_w   = (const float*)d_in[5];
    const float* qkv_b   = (const float*)d_in[6];
    const float* proj_w  = (const float*)d_in[7];
    const float* proj_b  = (const float*)d_in[8];
    const int*   d_start = (const int*)d_in[9];
    float* out = (float*)d_out;
    char* ws = (char*)d_ws;

    // layout: x_ln [0,1M) | qkv [1M,4M) | part [4M,12M) | accp [4M,20M) |
    // mlp [20M,20.25M) | attn_out [21M,22M).
    // sequential reuse: qkv-gemm partials consumed by combine BEFORE attn
    // writes accp; proj partials [4M,12M) written AFTER attn_combine reads accp.
    float* x_ln     = (float*)ws;
    float* qkv      = (float*)(ws + (1u<<20));
    float* part     = (float*)(ws + (4u<<20));
    float* accp     = (float*)(ws + (4u<<20));
    float* mlp      = (float*)(ws + (20u<<20));
    float* attn_out = (float*)(ws + (21u<<20));

    ln_kernel<<<MM, 256, 0, stream>>>(tokens, gamma, beta, x_ln);
    gemm_mfma<<<dim3(QKV_N/64, 4), 256, 0, stream>>>(x_ln, qkv_w, part, QKV_N, HID, 4);
    combine_bias<<<(MM*QKV_N/4 + 255)/256, 256, 0, stream>>>(part, qkv_b, qkv, QKV_N, MM*QKV_N/4, 4);
    attn_part<<<dim3(BB*NH, NCHUNK), 256, 0, stream>>>(qkv, cache_k, cache_v, d_start, accp, mlp);
    attn_combine<<<BB*NH, 256, 0, stream>>>(accp, mlp, attn_out);
    gemm_mfma<<<dim3(HID/64, 8), 256, 0, stream>>>(attn_out, proj_w, part, HID, HID, 8);
    combine_bias<<<(MM*HID/4 + 255)/256, 256, 0, stream>>>(part, proj_b, out, HID, MM*HID/4, 8);
}

// Round 11
// 293.046 us; speedup vs baseline: 1.0425x; 1.0425x over previous
//
#include <hip/hip_runtime.h>
#include <math.h>

#define HID 4096
#define NH 32
#define HD 128
#define BB 8
#define SS 8
#define MM 64              // B*S rows
#define MAXT 4096
#define QKV_N (3*HID)      // 12288
#define GBK 64             // GEMM K-step
#define ASTR 72            // GEMM LDS row stride (bf16)

// attention geometry (r8 grid shape + r10 inner loop)
#define ATILE 64                 // K/V rows per staged tile
#define ACHUNK 2048              // t-rows per block
#define NCHUNK (MAXT/ACHUNK)     // 2
#define NTILES (ACHUNK/ATILE)    // 32
#define NPART (NCHUNK*4)         // partials per (b,h) = 8
#define KSTR 136                 // K LDS row stride (bf16)
#define VSTR 72                  // V^T LDS t-stride (bf16)

typedef __attribute__((ext_vector_type(8))) __bf16 bf16x8;
typedef __attribute__((ext_vector_type(4))) __bf16 bf16x4;
typedef __attribute__((ext_vector_type(4))) float f32x4;
typedef __attribute__((ext_vector_type(4))) short s16x4;

__device__ __forceinline__ float wred_sum(float v) {
#pragma unroll
    for (int i = 1; i < 64; i <<= 1) v += __shfl_xor(v, i, 64);
    return v;
}
__device__ __forceinline__ short bf16bits(float x) {
    __bf16 h = (__bf16)x;
    return __builtin_bit_cast(short, h);
}

// -------------------- LayerNorm: 64 rows of 4096 --------------------
__global__ __launch_bounds__(256)
void ln_kernel(const float* __restrict__ tokens, const float* __restrict__ gamma,
               const float* __restrict__ beta, float* __restrict__ xout) {
    const int row = blockIdx.x;
    const float* in = tokens + (size_t)row * HID;
    float* out = xout + (size_t)row * HID;
    const int tid = threadIdx.x;
    float s = 0.f, s2 = 0.f;
    float4 vals[4];
#pragma unroll
    for (int i = 0; i < 4; ++i) {
        float4 v = *(const float4*)(in + (size_t)(i*256 + tid)*4);
        vals[i] = v;
        s  += v.x + v.y + v.z + v.w;
        s2 += v.x*v.x + v.y*v.y + v.z*v.z + v.w*v.w;
    }
    s = wred_sum(s); s2 = wred_sum(s2);
    __shared__ float red[8];
    int wid = tid >> 6, lane = tid & 63;
    if (lane == 0) { red[wid] = s; red[4+wid] = s2; }
    __syncthreads();
    s  = red[0]+red[1]+red[2]+red[3];
    s2 = red[4]+red[5]+red[6]+red[7];
    float mean = s * (1.f/HID);
    float var  = s2 * (1.f/HID) - mean*mean;
    float rstd = rsqrtf(var + 1e-5f);
#pragma unroll
    for (int i = 0; i < 4; ++i) {
        int base = (i*256 + tid)*4;
        float4 v = vals[i];
        float4 g  = *(const float4*)(gamma + base);
        float4 bt = *(const float4*)(beta + base);
        float4 o;
        o.x = (v.x - mean)*rstd*g.x + bt.x;
        o.y = (v.y - mean)*rstd*g.y + bt.y;
        o.z = (v.z - mean)*rstd*g.z + bt.z;
        o.w = (v.w - mean)*rstd*g.w + bt.w;
        *(float4*)(out + base) = o;
    }
}

// ---------- split-bf16 MFMA GEMM (unchanged from r8) ----------
__global__ __launch_bounds__(256, 3)
void gemm_mfma(const float* __restrict__ x, const float* __restrict__ w,
               float* __restrict__ part, int N, int K, int kparts) {
    __shared__ __bf16 a_hi[64*ASTR], a_lo[64*ASTR];
    __shared__ __bf16 b_hi[64*ASTR], b_lo[64*ASTR];
    const int n0 = blockIdx.x * 64;
    const int kc = blockIdx.y;
    const int kLen = K / kparts;
    const int kBeg = kc * kLen;
    const int tid = threadIdx.x;
    const int wv = tid >> 6;
    const int lane = tid & 63;
    const int wm = (wv & 1) * 32;
    const int wn = (wv >> 1) * 32;
    const int sr = tid >> 2;
    const int sk = (tid & 3) * 16;
    const int fm = lane & 15;
    const int fk = (lane >> 4) * 8;

    f32x4 acc[2][2] = {};
    const float* xsrc = x + (size_t)sr * K + kBeg + sk;
    const float* wsrc = w + (size_t)(n0 + sr) * K + kBeg + sk;

    float aRg[16], bRg[16];
#pragma unroll
    for (int q = 0; q < 4; ++q) {
        *(float4*)&aRg[q*4] = *(const float4*)(xsrc + q*4);
        *(float4*)&bRg[q*4] = *(const float4*)(wsrc + q*4);
    }
    const int nsteps = kLen / GBK;
    for (int st = 0; st < nsteps; ++st) {
        __syncthreads();
#pragma unroll
        for (int q = 0; q < 2; ++q) {
            bf16x8 ah, al, bh, bl;
#pragma unroll
            for (int j = 0; j < 8; ++j) {
                float av = aRg[q*8+j];
                __bf16 h = (__bf16)av;
                ah[j] = h;
                al[j] = (__bf16)(av - (float)h);
                float bv = bRg[q*8+j];
                __bf16 g = (__bf16)bv;
                bh[j] = g;
                bl[j] = (__bf16)(bv - (float)g);
            }
            int base = sr*ASTR + sk + q*8;
            *(bf16x8*)&a_hi[base] = ah;
            *(bf16x8*)&a_lo[base] = al;
            *(bf16x8*)&b_hi[base] = bh;
            *(bf16x8*)&b_lo[base] = bl;
        }
        __syncthreads();
        if (st + 1 < nsteps) {
            const float* xn = xsrc + (size_t)(st+1)*GBK;
            const float* wn_ = wsrc + (size_t)(st+1)*GBK;
#pragma unroll
            for (int q = 0; q < 4; ++q) {
                *(float4*)&aRg[q*4] = *(const float4*)(xn + q*4);
                *(float4*)&bRg[q*4] = *(const float4*)(wn_ + q*4);
            }
        }
#pragma unroll
        for (int kh = 0; kh < 2; ++kh) {
            bf16x8 Ah[2], Al[2], Bh[2], Bl[2];
#pragma unroll
            for (int t = 0; t < 2; ++t) {
                int ar = (wm + t*16 + fm)*ASTR + kh*32 + fk;
                Ah[t] = *(const bf16x8*)&a_hi[ar];
                Al[t] = *(const bf16x8*)&a_lo[ar];
                int br = (wn + t*16 + fm)*ASTR + kh*32 + fk;
                Bh[t] = *(const bf16x8*)&b_hi[br];
                Bl[t] = *(const bf16x8*)&b_lo[br];
            }
#pragma unroll
            for (int mt = 0; mt < 2; ++mt)
#pragma unroll
            for (int nt = 0; nt < 2; ++nt) {
                acc[mt][nt] = __builtin_amdgcn_mfma_f32_16x16x32_bf16(Ah[mt], Bh[nt], acc[mt][nt], 0, 0, 0);
                acc[mt][nt] = __builtin_amdgcn_mfma_f32_16x16x32_bf16(Ah[mt], Bl[nt], acc[mt][nt], 0, 0, 0);
                acc[mt][nt] = __builtin_amdgcn_mfma_f32_16x16x32_bf16(Al[mt], Bh[nt], acc[mt][nt], 0, 0, 0);
            }
        }
    }
    float* dst = part + (size_t)kc * MM * N;
#pragma unroll
    for (int mt = 0; mt < 2; ++mt)
#pragma unroll
    for (int nt = 0; nt < 2; ++nt) {
        int m = wm + mt*16 + (lane >> 4)*4;
        int n = n0 + wn + nt*16 + (lane & 15);
#pragma unroll
        for (int r = 0; r < 4; ++r)
            dst[(size_t)(m + r) * N + n] = acc[mt][nt][r];
    }
}

// ---------------- sum nparts partials + bias ----------------
__global__ __launch_bounds__(256)
void combine_bias(const float* __restrict__ part, const float* __restrict__ bias,
                  float* __restrict__ out, int N, int totalv4, int nparts) {
    int idx = blockIdx.x * 256 + threadIdx.x;
    if (idx >= totalv4) return;
    size_t base = (size_t)idx * 4;
    size_t MN = (size_t)MM * N;
    float4 o = make_float4(0.f,0.f,0.f,0.f);
    for (int p = 0; p < nparts; ++p) {
        float4 a = *(const float4*)(part + (size_t)p * MN + base);
        o.x += a.x; o.y += a.y; o.z += a.z; o.w += a.w;
    }
    int n = (int)(base % (size_t)N);
    float4 bb = *(const float4*)(bias + n);
    o.x += bb.x; o.y += bb.y; o.z += bb.z; o.w += bb.w;
    *(float4*)(out + base) = o;
}

// ---------------- MFMA flash attention partial ----------------
// r11 = r8 grid geometry (NCHUNK=2, 512 blocks = one resident generation,
// NO min-waves bound -> compiler-chosen VGPR, no spill) + r10 inner loop
// (k=16 PV with lane-local P: no p_lds, no pad zeroing, LDS 35.8KB).
__global__ __launch_bounds__(256)
void attn_part(const float* __restrict__ qkv, const float* __restrict__ cache_k,
               const float* __restrict__ cache_v, const int* __restrict__ d_start,
               float* __restrict__ accp, float* __restrict__ mlp) {
    __shared__ __bf16 k_lds[ATILE*KSTR];   // 17408 B  [t][d]
    __shared__ __bf16 v_lds[HD*VSTR];      // 18432 B  [d][t] (transposed)
    const int bh = blockIdx.x;
    const int b = bh >> 5, h = bh & 31;
    const int c = blockIdx.y;
    const int tid = threadIdx.x;
    const int w = tid >> 6;
    const int lane = tid & 63;
    const int l15 = lane & 15;
    const int lg  = lane >> 4;          // frag quadrant 0..3
    const int woff = w * 16;            // wave's t-rows within tile
    const int start = d_start[0];
    const int T = start + SS;
    const float scale = 0.08838834764831845f;   // 1/sqrt(128)

    const int tq = tid >> 5;            // staging rows tq*8..tq*8+8 (covers 0..63)
    const int d4 = (tid & 31) * 4;      // staging d offset

    const size_t cacheRowBase = ((size_t)b*MAXT*NH + h) * (size_t)HD;
    const int cbase = c * ACHUNK;

    float4 kreg[8], vreg[8];
#define LOAD_TILE(TB)                                                             \
    {                                                                             \
        _Pragma("unroll")                                                         \
        for (int j = 0; j < 8; ++j) {                                             \
            int tg = (TB) + tq*8 + j;                                             \
            bool fresh = (tg >= start) && (tg < T);                               \
            const float* kp = fresh                                               \
                ? (qkv + (size_t)(b*SS + (tg-start))*QKV_N + h*HD + HID)          \
                : (cache_k + cacheRowBase + (size_t)tg*NH*HD);                    \
            const float* vp = fresh                                               \
                ? (qkv + (size_t)(b*SS + (tg-start))*QKV_N + h*HD + 2*HID)        \
                : (cache_v + cacheRowBase + (size_t)tg*NH*HD);                    \
            kreg[j] = *(const float4*)(kp + d4);                                  \
            vreg[j] = *(const float4*)(vp + d4);                                  \
        }                                                                         \
    }

    // ---- prologue: Q fragments (regs for whole kernel) ----
    bf16x8 qf[4];
    if (l15 < SS) {
        const float* qp = qkv + (size_t)(b*SS + l15)*QKV_N + h*HD + lg*8;
#pragma unroll
        for (int ks = 0; ks < 4; ++ks) {
            float4 a = *(const float4*)(qp + ks*32);
            float4 b2 = *(const float4*)(qp + ks*32 + 4);
            bf16x8 q8;
            q8[0]=(__bf16)a.x;  q8[1]=(__bf16)a.y;  q8[2]=(__bf16)a.z;  q8[3]=(__bf16)a.w;
            q8[4]=(__bf16)b2.x; q8[5]=(__bf16)b2.y; q8[6]=(__bf16)b2.z; q8[7]=(__bf16)b2.w;
            qf[ks] = q8;
        }
    } else {
#pragma unroll
        for (int ks = 0; ks < 4; ++ks) qf[ks] = (bf16x8)(__bf16)0.0f;
    }
    LOAD_TILE(cbase);
    __syncthreads();

    float m_r = -1e30f, l_r = 0.f;
    f32x4 oacc[8] = {};

    for (int tile = 0; tile < NTILES; ++tile) {
        const int tbase = cbase + tile*ATILE;
        // ---- convert staged regs -> LDS (K row-major bf16, V transposed) ----
#pragma unroll
        for (int j = 0; j < 8; ++j) {
            bf16x4 kb;
            kb[0]=(__bf16)kreg[j].x; kb[1]=(__bf16)kreg[j].y;
            kb[2]=(__bf16)kreg[j].z; kb[3]=(__bf16)kreg[j].w;
            *(bf16x4*)&k_lds[(tq*8+j)*KSTR + d4] = kb;
        }
#pragma unroll
        for (int i = 0; i < 4; ++i) {
            bf16x8 vt;
#pragma unroll
            for (int j = 0; j < 8; ++j)
                vt[j] = (__bf16)(((const float*)&vreg[j])[i]);
            *(bf16x8*)&v_lds[(d4 + i)*VSTR + tq*8] = vt;
        }
        __syncthreads();   // tile LDS ready
        if (tile + 1 < NTILES) LOAD_TILE(tbase + ATILE);   // lands under compute

        // ---- QK^T (k=32): D[t_loc=lg*4+r][s=l15] ----
        f32x4 sacc = {0.f, 0.f, 0.f, 0.f};
#pragma unroll
        for (int ks = 0; ks < 4; ++ks) {
            bf16x8 kf = *(const bf16x8*)&k_lds[(woff + l15)*KSTR + ks*32 + lg*8];
            sacc = __builtin_amdgcn_mfma_f32_16x16x32_bf16(kf, qf[ks], sacc, 0, 0, 0);
        }
        // ---- online softmax (per wave; lane: s=l15, t=lg*4+r) ----
        float sc[4]; bool val[4];
#pragma unroll
        for (int r = 0; r < 4; ++r) {
            int tg = tbase + woff + lg*4 + r;
            val[r] = tg < T;
            sc[r] = val[r] ? sacc[r]*scale : -1e30f;
        }
        float tmax = fmaxf(fmaxf(sc[0], sc[1]), fmaxf(sc[2], sc[3]));
        tmax = fmaxf(tmax, __shfl_xor(tmax, 16, 64));
        tmax = fmaxf(tmax, __shfl_xor(tmax, 32, 64));
        float mn = fmaxf(m_r, tmax);
        float al = __expf(m_r - mn);
        float p[4];
#pragma unroll
        for (int r = 0; r < 4; ++r) p[r] = val[r] ? __expf(sc[r] - mn) : 0.f;
        float psum = (p[0]+p[1]) + (p[2]+p[3]);
        psum += __shfl_xor(psum, 16, 64);
        psum += __shfl_xor(psum, 32, 64);
        l_r = l_r * al + psum;
        m_r = mn;
        // ---- PV (k=16): pa = own p (A[m=s=l15][k=t=lg*4+j] = p[j]) ----
        s16x4 pa;
        pa[0]=bf16bits(p[0]); pa[1]=bf16bits(p[1]);
        pa[2]=bf16bits(p[2]); pa[3]=bf16bits(p[3]);
        // rescale oacc rows (s=lg*4+r) by their alpha
        float als[4];
#pragma unroll
        for (int r = 0; r < 4; ++r) als[r] = __shfl(al, lg*4 + r, 64);
#pragma unroll
        for (int dt = 0; dt < 8; ++dt) {
            oacc[dt][0] *= als[0]; oacc[dt][1] *= als[1];
            oacc[dt][2] *= als[2]; oacc[dt][3] *= als[3];
        }
#pragma unroll
        for (int dt = 0; dt < 8; ++dt) {
            s16x4 vb = *(const s16x4*)&v_lds[(dt*16 + l15)*VSTR + woff + lg*4];
            oacc[dt] = __builtin_amdgcn_mfma_f32_16x16x16bf16_1k(pa, vb, oacc[dt], 0, 0, 0);
        }
        __syncthreads();   // all readers done before next convert
    }

    // ---- store per-wave partial: acc rows s<8, m, l ----
    const int pidx = (bh*NCHUNK + c)*4 + w;
    float* abase = accp + (size_t)pidx * SS * HD;
#pragma unroll
    for (int r = 0; r < 4; ++r) {
        int s = lg*4 + r;
        if (s < SS) {
#pragma unroll
            for (int dt = 0; dt < 8; ++dt)
                abase[(size_t)s*HD + dt*16 + l15] = oacc[dt][r];
        }
    }
    if (lane < SS) {
        mlp[(size_t)pidx*16 + lane] = m_r;
        mlp[(size_t)pidx*16 + 8 + lane] = l_r;
    }
#undef LOAD_TILE
}

// ---------------- combine NPART partials -> attn_out (64 x 4096) ----------------
__global__ __launch_bounds__(256)
void attn_combine(const float* __restrict__ accp, const float* __restrict__ mlp,
                  float* __restrict__ attn_out) {
    const int bh = blockIdx.x;
    const int b = bh >> 5, h = bh & 31;
    const int tid = threadIdx.x;
    const int s = tid >> 5, dg = tid & 31;
    float mC[NPART], lC[NPART];
    float M = -1e30f;
#pragma unroll
    for (int p = 0; p < NPART; ++p) {
        size_t mb = (size_t)(bh*NPART + p) * 16;
        mC[p] = mlp[mb + s];
        lC[p] = mlp[mb + 8 + s];
        M = fmaxf(M, mC[p]);
    }
    float L = 0.f;
    float4 o = make_float4(0.f,0.f,0.f,0.f);
#pragma unroll
    for (int p = 0; p < NPART; ++p) {
        float wgt = __expf(mC[p] - M);
        L += wgt * lC[p];
        float4 a = *(const float4*)(accp + ((size_t)(bh*NPART + p) * SS + s) * HD + dg*4);
        o.x += wgt*a.x; o.y += wgt*a.y; o.z += wgt*a.z; o.w += wgt*a.w;
    }
    float inv = 1.f / L;
    o.x *= inv; o.y *= inv; o.z *= inv; o.w *= inv;
    *(float4*)(attn_out + (size_t)(b*SS + s)*HID + h*HD + dg*4) = o;
}

extern "C" void kernel_launch(void* const* d_in, const int* in_sizes, int n_in,
                              void* d_out, int out_size, void* d_ws, size_t ws_size,
                              hipStream_t stream) {
    const float* tokens  = (const float*)d_in[0];
    const float* cache_k = (const float*)d_in[1];
    const float* cache_v = (const float*)d_in[2];
    const float* gamma   = (const float*)d_in[3];
    const float* beta    = (const float*)d_in[4];
    const float* qkv_w   = (const float*)d_in[5];
    const float* qkv_b   = (const float*)d_in[6];
    const float* proj_w  = (const float*)d_in[7];
    const float* proj_b  = (const float*)d_in[8];
    const int*   d_start = (const int*)d_in[9];
    float* out = (float*)d_out;
    char* ws = (char*)d_ws;

    // layout: x_ln [0,1M) | qkv [1M,4M) | part/accp [4M,13M) | mlp [13M,13.25M)
    // | attn_out [16M,17M). sequential reuse: qkv partials consumed before accp
    // written; proj partials [4M,12M) written after attn_combine reads accp.
    float* x_ln     = (float*)ws;
    float* qkv      = (float*)(ws + (1u<<20));
    float* part     = (float*)(ws + (4u<<20));
    float* accp     = (float*)(ws + (4u<<20));
    float* mlp      = (float*)(ws + (13u<<20));
    float* attn_out = (float*)(ws + (16u<<20));

    ln_kernel<<<MM, 256, 0, stream>>>(tokens, gamma, beta, x_ln);
    gemm_mfma<<<dim3(QKV_N/64, 4), 256, 0, stream>>>(x_ln, qkv_w, part, QKV_N, HID, 4);
    combine_bias<<<(MM*QKV_N/4 + 255)/256, 256, 0, stream>>>(part, qkv_b, qkv, QKV_N, MM*QKV_N/4, 4);
    attn_part<<<dim3(BB*NH, NCHUNK), 256, 0, stream>>>(qkv, cache_k, cache_v, d_start, accp, mlp);
    attn_combine<<<BB*NH, 256, 0, stream>>>(accp, mlp, attn_out);
    gemm_mfma<<<dim3(HID/64, 8), 256, 0, stream>>>(attn_out, proj_w, part, HID, HID, 8);
    combine_bias<<<(MM*HID/4 + 255)/256, 256, 0, stream>>>(part, proj_b, out, HID, MM*HID/4, 8);
}